// Round 11
// baseline (201.198 us; speedup 1.0000x reference)
//
#include <hip/hip_runtime.h>
#include <math.h>

#define MROWS 8192   // T*B flat rows
#define DM    512    // d_model
#define SEQL  2048   // attention sequence (rows per batch group)
#define HDIM  64

typedef __attribute__((ext_vector_type(4))) float floatx4;
typedef _Float16 half2v __attribute__((ext_vector_type(2)));
typedef _Float16 half4v __attribute__((ext_vector_type(4)));
typedef _Float16 half8v __attribute__((ext_vector_type(8)));

#define CEXP 0.18033688011f   // log2(e)/8 — folded into Wq/bq at prep time

// async global->LDS, 16B per lane; LDS dst must be uniform_base + lane*16
__device__ __forceinline__ void gll16(const void* g, void* l) {
    __builtin_amdgcn_global_load_lds(
        (const __attribute__((address_space(1))) unsigned int*)g,
        (__attribute__((address_space(3))) unsigned int*)l, 16, 0, 0);
}

__device__ __forceinline__ half4v pack4(float a, float b, float c, float d) {
    half2v lo = __builtin_bit_cast(half2v, __builtin_amdgcn_cvt_pkrtz(a, b));
    half2v hi = __builtin_bit_cast(half2v, __builtin_amdgcn_cvt_pkrtz(c, d));
    half4v r;
    r[0] = lo[0]; r[1] = lo[1]; r[2] = hi[0]; r[3] = hi[1];
    return r;
}

// ---------------------------------------------------------------------------
// transpose+cast 512x512 f32 weights -> f16 [N][K]; Wq (z==0) pre-scaled by CEXP
// ---------------------------------------------------------------------------
__global__ __launch_bounds__(256) void transw(const float* __restrict__ w0,
                                              const float* __restrict__ w1,
                                              const float* __restrict__ w2,
                                              const float* __restrict__ w3,
                                              _Float16* __restrict__ t0,
                                              _Float16* __restrict__ t1,
                                              _Float16* __restrict__ t2,
                                              _Float16* __restrict__ t3) {
    __shared__ float tile[32][33];
    const float* W = blockIdx.z == 0 ? w0 : (blockIdx.z == 1 ? w1 : (blockIdx.z == 2 ? w2 : w3));
    _Float16* T = blockIdx.z == 0 ? t0 : (blockIdx.z == 1 ? t1 : (blockIdx.z == 2 ? t2 : t3));
    const float sc = (blockIdx.z == 0) ? CEXP : 1.0f;
    const int tx = threadIdx.x & 31, ty = threadIdx.x >> 5;  // 32 x 8
    const int x = blockIdx.x * 32 + tx;
    const int y0 = blockIdx.y * 32;
#pragma unroll
    for (int i = 0; i < 4; ++i)
        tile[ty + i * 8][tx] = W[(size_t)(y0 + ty + i * 8) * DM + x];
    __syncthreads();
    const int xo = y0 + tx;
#pragma unroll
    for (int i = 0; i < 4; ++i)
        T[(size_t)(blockIdx.x * 32 + ty + i * 8) * DM + xo] = (_Float16)(tile[tx][ty + i * 8] * sc);
}

// ---------------------------------------------------------------------------
// Projection GEMM, 128x128 tile, BK=64 (r5 structure, unchanged).
// ---------------------------------------------------------------------------
__global__ __launch_bounds__(256, 3) void proj_gemm(
        const float* __restrict__ q32, const float* __restrict__ k32, const float* __restrict__ v32,
        const _Float16* __restrict__ Wq, const _Float16* __restrict__ Wk, const _Float16* __restrict__ Wv,
        const float* __restrict__ bq, const float* __restrict__ bk, const float* __restrict__ bv,
        _Float16* __restrict__ Qo, _Float16* __restrict__ Ko, _Float16* __restrict__ Vto) {
    __shared__ _Float16 As[128 * 64];   // 16 KB [m][k], xor-swizzled 16B groups
    __shared__ _Float16 Bs[128 * 64];   // 16 KB [n][k], xor-swizzled
    const int z = blockIdx.z;
    const float* A32    = z == 0 ? q32 : (z == 1 ? k32 : v32);
    const _Float16* Bt  = z == 0 ? Wq : (z == 1 ? Wk : Wv);
    const float* bias   = z == 0 ? bq : (z == 1 ? bk : bv);
    const float bscale  = z == 0 ? CEXP : 1.0f;

    const int tid = threadIdx.x;
    const int w = tid >> 6, wr = w >> 1, wc = w & 1;   // 2x2 wave grid
    const int l15 = tid & 15, quad = (tid & 63) >> 4;
    const int m0 = blockIdx.x * 128, n0 = blockIdx.y * 128;

    // A staging: 2 threads per row, 32 f32 each (8 float4 -> 4 swizzled 16B)
    const int arow = tid >> 1, ah = tid & 1;
    const float* Asrc = &A32[(size_t)(m0 + arow) * DM + ah * 32];
    _Float16* Adst = &As[arow * 64];
    const int asw = arow & 7;

    floatx4 acc[4][4];
#pragma unroll
    for (int i = 0; i < 4; ++i)
#pragma unroll
        for (int j = 0; j < 4; ++j) acc[i][j] = (floatx4){0.f, 0.f, 0.f, 0.f};

    for (int kt = 0; kt < DM / 64; ++kt) {   // 8 iters
        __syncthreads();
        // A reg-loads first (issued before gll16s: cast waits at vmcnt(4))
        floatx4 f[8];
        {
            const float* s = Asrc + (size_t)kt * 64;
#pragma unroll
            for (int q = 0; q < 8; ++q) f[q] = *(const floatx4*)&s[q * 4];
        }
        // B: 128 rows x 64 k = 1024 chunks of 16B -> 4 gll16/thread
#pragma unroll
        for (int i = 0; i < 4; ++i) {
            const int c = i * 256 + tid;
            const int row = c >> 3, g = c & 7;
            const int kg = g ^ (row & 7);
            gll16(&Bt[(size_t)(n0 + row) * DM + kt * 64 + kg * 8], &Bs[c * 8]);
        }
        // A cast + swizzled LDS writes
#pragma unroll
        for (int t = 0; t < 4; ++t) {
            half8v o;
            o[0] = (_Float16)f[2 * t][0]; o[1] = (_Float16)f[2 * t][1];
            o[2] = (_Float16)f[2 * t][2]; o[3] = (_Float16)f[2 * t][3];
            o[4] = (_Float16)f[2 * t + 1][0]; o[5] = (_Float16)f[2 * t + 1][1];
            o[6] = (_Float16)f[2 * t + 1][2]; o[7] = (_Float16)f[2 * t + 1][3];
            const int g = ah * 4 + t;
            *(half8v*)&Adst[(g ^ asw) * 8] = o;
        }
        __syncthreads();
#pragma unroll
        for (int ks = 0; ks < 2; ++ks) {
            half8v af[4], bf[4];
#pragma unroll
            for (int i = 0; i < 4; ++i) {
                const int row = wr * 64 + i * 16 + l15;
                af[i] = *(const half8v*)&As[row * 64 + (((ks * 4 + quad)) ^ (row & 7)) * 8];
            }
#pragma unroll
            for (int j = 0; j < 4; ++j) {
                const int row = wc * 64 + j * 16 + l15;
                bf[j] = *(const half8v*)&Bs[row * 64 + (((ks * 4 + quad)) ^ (row & 7)) * 8];
            }
#pragma unroll
            for (int i = 0; i < 4; ++i)
#pragma unroll
                for (int j = 0; j < 4; ++j)
                    acc[i][j] = __builtin_amdgcn_mfma_f32_16x16x32_f16(af[i], bf[j], acc[i][j], 0, 0, 0);
        }
    }
    // epilogue
#pragma unroll
    for (int j = 0; j < 4; ++j) {
        const int col = n0 + wc * 64 + j * 16 + l15;
        const float bv4 = bias[col] * bscale;
#pragma unroll
        for (int i = 0; i < 4; ++i) {
            const int rb = m0 + wr * 64 + i * 16 + quad * 4;
            if (z == 2) {   // Vt[g][col][seq]: 4 consecutive seq -> one 8B store
                const int g = rb >> 11, seq = rb & 2047;
                half4v pv;
#pragma unroll
                for (int r = 0; r < 4; ++r) pv[r] = (_Float16)(acc[i][j][r] + bv4);
                *(half4v*)&Vto[((size_t)g * DM + col) * SEQL + seq] = pv;
            } else {
                _Float16* oh = z == 0 ? Qo : Ko;
#pragma unroll
                for (int r = 0; r < 4; ++r)
                    oh[(size_t)(rb + r) * DM + col] = (_Float16)(acc[i][j][r] + bv4);
            }
        }
    }
}

// ---------------------------------------------------------------------------
// Output GEMM: out = O16 . Wo + bo.  A (normalized O, f16) staged via gll16
// directly.  block = 32 M x 256 N, BK=64, grid (2, 256).  (r8 version.)
// ---------------------------------------------------------------------------
__global__ __launch_bounds__(256, 4) void out_gemm(
        const _Float16* __restrict__ O16,
        const _Float16* __restrict__ Wo, const float* __restrict__ bo,
        float* __restrict__ out) {
    __shared__ _Float16 Bs[256 * 64];   // 32 KB
    __shared__ _Float16 As[32 * 64];    //  4 KB
    const int tid = threadIdx.x;
    const int w = tid >> 6;
    const int l15 = tid & 15, quad = (tid & 63) >> 4;
    const int n0 = blockIdx.x * 256, m0 = blockIdx.y * 32;

    // A gll16 geometry: 32 rows x 64 k = 256 chunks of 16B -> 1 per thread
    const int arow = tid >> 3, ag = tid & 7;
    const int akg = ag ^ (arow & 7);

    floatx4 acc[2][4];
#pragma unroll
    for (int i = 0; i < 2; ++i)
#pragma unroll
        for (int j = 0; j < 4; ++j) acc[i][j] = (floatx4){0.f, 0.f, 0.f, 0.f};

    for (int kt = 0; kt < DM / 64; ++kt) {   // 8 iters
        __syncthreads();
        // B: 256 rows x 64 k = 2048 chunks -> 8 gll16/thread
#pragma unroll
        for (int i = 0; i < 8; ++i) {
            const int c = i * 256 + tid;
            const int row = c >> 3, g = c & 7;
            const int kg = g ^ (row & 7);
            gll16(&Wo[(size_t)(n0 + row) * DM + kt * 64 + kg * 8], &Bs[c * 8]);
        }
        // A: 1 gll16/thread
        gll16(&O16[(size_t)(m0 + arow) * DM + kt * 64 + akg * 8], &As[tid * 8]);
        __syncthreads();
#pragma unroll
        for (int ks = 0; ks < 2; ++ks) {
            half8v af[2], bfr[4];
#pragma unroll
            for (int i = 0; i < 2; ++i) {
                const int row = i * 16 + l15;
                af[i] = *(const half8v*)&As[row * 64 + ((ks * 4 + quad) ^ (row & 7)) * 8];
            }
#pragma unroll
            for (int j = 0; j < 4; ++j) {
                const int row = w * 64 + j * 16 + l15;
                bfr[j] = *(const half8v*)&Bs[row * 64 + ((ks * 4 + quad) ^ (row & 7)) * 8];
            }
#pragma unroll
            for (int i = 0; i < 2; ++i)
#pragma unroll
                for (int j = 0; j < 4; ++j)
                    acc[i][j] = __builtin_amdgcn_mfma_f32_16x16x32_f16(af[i], bfr[j], acc[i][j], 0, 0, 0);
        }
    }
#pragma unroll
    for (int j = 0; j < 4; ++j) {
        const int col = n0 + w * 64 + j * 16 + l15;
        const float bv4 = bo[col];
#pragma unroll
        for (int i = 0; i < 2; ++i) {
            const int rb = m0 + i * 16 + quad * 4;
#pragma unroll
            for (int r = 0; r < 4; ++r)
                out[(size_t)(rb + r) * DM + col] = acc[i][j][r] + bv4;
        }
    }
}

// ---------------------------------------------------------------------------
// Flash attention, f16 MFMA, S^T orientation, fixed-scale softmax.
// r11: 512-thread blocks — 8 waves x 16 q-rows (q=128/block, 512 blocks as
// r10) -> 4 waves/SIMD instead of 2, SAME staging traffic and K/V reuse.
// r10's swizzle showed attn isn't memory-bound (FETCH 12 MB); the serial
// chain per wave (QK MFMA -> 32 exp2 -> PV MFMA) with only 2 waves/SIMD is
// the latency theory this tests unconfounded (r6/r9 also doubled work).
// XCD swizzle (T1) + in-register normalization kept.  LDS 32 KB.
// grid (16 q-tiles, 32 (g,h) pairs); 512 threads.
// ---------------------------------------------------------------------------
__global__ __launch_bounds__(512, 4) void attn_mfma(const _Float16* __restrict__ Q16,
                                                    const _Float16* __restrict__ K16,
                                                    const _Float16* __restrict__ Vt,
                                                    _Float16* __restrict__ O16) {
    __shared__ _Float16 Ks[2][64 * 64];   // [key][d], xor-swizzled d-groups
    __shared__ _Float16 Vs[2][64 * 64];   // [d][key], xor-swizzled key-groups

    const int tid  = threadIdx.x;
    const int lane = tid & 63;
    const int wid  = tid >> 6;            // 0..7
    const int l15  = lane & 15;
    const int quad = lane >> 4;

    // XCD swizzle: linear id -> chunked id so each XCD (id%8 under round-robin
    // dispatch) covers 64 consecutive logical blocks = 4 pairs x 16 q-tiles.
    const int idl  = blockIdx.y * 16 + blockIdx.x;     // 0..511
    const int swz  = (idl & 7) * 64 + (idl >> 3);      // bijective (512%8==0)
    const int pair = swz >> 4;
    const int grp  = pair >> 3;
    const int h    = pair & 7;
    const int q0   = (swz & 15) * 128;
    const int rQ   = grp * SEQL + q0 + wid * 16;       // 16 q-rows per wave
    const int cb   = h * HDIM;
    const int NIT  = SEQL / 64;   // 32

    const _Float16* Kbase = K16 + (size_t)grp * SEQL * DM + cb;
    const _Float16* Vbase = Vt + (size_t)grp * DM * SEQL + (size_t)cb * SEQL;

    // Q fragments (B-operand of S^T): B[n=qrow=l15][k=d=quad*8+j]
    half8v qf[2];
#pragma unroll
    for (int ks = 0; ks < 2; ++ks)
        qf[ks] = *(const half8v*)&Q16[(size_t)(rQ + l15) * DM + cb + ks * 32 + quad * 8];

    floatx4 oacc[4], lacc;
    lacc = (floatx4){0.f, 0.f, 0.f, 0.f};
#pragma unroll
    for (int dt = 0; dt < 4; ++dt) oacc[dt] = (floatx4){0.f, 0.f, 0.f, 0.f};
    half4v ones;
    ones[0] = (_Float16)1.f; ones[1] = (_Float16)1.f; ones[2] = (_Float16)1.f; ones[3] = (_Float16)1.f;

    // staging: 1024 chunks of 16B over 512 threads -> 2 gll16/thread
#define STAGE(KT, B)                                                            \
    {                                                                           \
        _Float16* ksb = &Ks[B][0];                                              \
        _Float16* vsb = &Vs[B][0];                                              \
        _Pragma("unroll")                                                       \
        for (int i_ = 0; i_ < 2; ++i_) {                                        \
            const int c_ = i_ * 512 + tid;                                      \
            if (c_ < 512) {                                                     \
                const int key_ = c_ >> 3, g_ = c_ & 7;                          \
                const int dg_ = g_ ^ (key_ & 7);                                \
                gll16(&Kbase[(size_t)((KT) * 64 + key_) * DM + dg_ * 8],        \
                      &ksb[c_ * 8]);                                            \
            } else {                                                            \
                const int cv_ = c_ - 512;                                       \
                const int d_ = cv_ >> 3, g_ = cv_ & 7;                          \
                const int kg_ = g_ ^ (d_ & 7);                                  \
                gll16(&Vbase[(size_t)d_ * SEQL + (KT) * 64 + kg_ * 8],          \
                      &vsb[cv_ * 8]);                                           \
            }                                                                   \
        }                                                                       \
    }

    STAGE(0, 0)

    for (int it = 0; it < NIT; ++it) {
        const int cur = it & 1;
        __syncthreads();               // data for it ready; prev readers done
        if (it + 1 < NIT) STAGE(it + 1, cur ^ 1)

        const _Float16* ksb = &Ks[cur][0];
        const _Float16* vsb = &Vs[cur][0];

        // S^T = K . Q^T : D[m=key][n=qrow]
        floatx4 st[4];
#pragma unroll
        for (int ktile = 0; ktile < 4; ++ktile) {
            const int key = ktile * 16 + l15;
            const half8v kf0 = *(const half8v*)&ksb[key * 64 + ((0 + quad) ^ (key & 7)) * 8];
            const half8v kf1 = *(const half8v*)&ksb[key * 64 + ((4 + quad) ^ (key & 7)) * 8];
            floatx4 z = {0.f, 0.f, 0.f, 0.f};
            z = __builtin_amdgcn_mfma_f32_16x16x32_f16(kf0, qf[0], z, 0, 0, 0);
            st[ktile] = __builtin_amdgcn_mfma_f32_16x16x32_f16(kf1, qf[1], z, 0, 0, 0);
        }

        // p = 2^s, straight into A-operand regs of 16x16x16 (k=key=quad*4+j)
        half4v pa[4];
#pragma unroll
        for (int ktile = 0; ktile < 4; ++ktile)
            pa[ktile] = pack4(__builtin_amdgcn_exp2f(st[ktile][0]),
                              __builtin_amdgcn_exp2f(st[ktile][1]),
                              __builtin_amdgcn_exp2f(st[ktile][2]),
                              __builtin_amdgcn_exp2f(st[ktile][3]));

        // l += P . ones  (same C-layout rows as O)
#pragma unroll
        for (int ktile = 0; ktile < 4; ++ktile)
            lacc = __builtin_amdgcn_mfma_f32_16x16x16f16(pa[ktile], ones, lacc, 0, 0, 0);

        // O += P . V : B[k=key=quad*4+j][n=d=l15] from Vs[d][key]
#pragma unroll
        for (int dt = 0; dt < 4; ++dt) {
            const int d = dt * 16 + l15;
#pragma unroll
            for (int ktile = 0; ktile < 4; ++ktile) {
                const int G = ktile * 2 + (quad >> 1);
                const int slot = G ^ (d & 7);
                const half4v vf = *(const half4v*)&vsb[d * 64 + slot * 8 + (quad & 1) * 4];
                oacc[dt] = __builtin_amdgcn_mfma_f32_16x16x16f16(pa[ktile], vf, oacc[dt], 0, 0, 0);
            }
        }
    }

    // epilogue: normalize in-register (lacc rows == oacc rows) + f16 store
#pragma unroll
    for (int r = 0; r < 4; ++r) {
        const int qrow = rQ + quad * 4 + r;
        const size_t rowoff = (size_t)qrow * DM + cb;
        const float inv = 1.0f / lacc[r];
#pragma unroll
        for (int dt = 0; dt < 4; ++dt)
            O16[rowoff + dt * 16 + l15] = (_Float16)(oacc[dt][r] * inv);
    }
}

// ---------------------------------------------------------------------------
extern "C" void kernel_launch(void* const* d_in, const int* in_sizes, int n_in,
                              void* d_out, int out_size, void* d_ws, size_t ws_size,
                              hipStream_t stream) {
    const float* key_in   = (const float*)d_in[0];
    const float* value_in = (const float*)d_in[1];
    const float* query_in = (const float*)d_in[2];
    const float* Wk = (const float*)d_in[3];
    const float* bk = (const float*)d_in[4];
    const float* Wv = (const float*)d_in[5];
    const float* bv = (const float*)d_in[6];
    const float* Wq = (const float*)d_in[7];
    const float* bq = (const float*)d_in[8];
    const float* Wo = (const float*)d_in[9];
    const float* bo = (const float*)d_in[10];
    float* out = (float*)d_out;

    const size_t MAT = (size_t)MROWS * DM;   // 4M elems
    _Float16* Q16  = (_Float16*)d_ws;        // 8 MB
    _Float16* K16  = Q16 + MAT;              // 8 MB
    _Float16* Vtb  = K16 + MAT;              // 8 MB (transposed V, written by proj z=2)
    _Float16* Wqt  = Vtb + MAT;              // 0.5 MB each
    _Float16* Wkt  = Wqt + DM * DM;
    _Float16* Wvt  = Wkt + DM * DM;
    _Float16* Wot  = Wvt + DM * DM;
    _Float16* O16  = Wot + DM * DM;          // 8 MB (normalized attn output)

    const dim3 blk(256);

    transw<<<dim3(16, 16, 4), blk, 0, stream>>>(Wq, Wk, Wv, Wo, Wqt, Wkt, Wvt, Wot);

    // fused cast + Q/K/V projections; V writes Vt layout directly
    proj_gemm<<<dim3(MROWS / 128, DM / 128, 3), blk, 0, stream>>>(
        query_in, key_in, value_in, Wqt, Wkt, Wvt, bq, bk, bv, Q16, K16, Vtb);

    // full-key attention, XCD-swizzled, 8 waves x 16 q-rows, in-reg norm
    attn_mfma<<<dim3(SEQL / 128, 32), dim3(512), 0, stream>>>(Q16, K16, Vtb, O16);

    // output GEMM (plain m97 structure, both operands via gll16)
    out_gemm<<<dim3(2, MROWS / 32), blk, 0, stream>>>(O16, Wot, bo, out);
}

// Round 12
// 197.544 us; speedup vs baseline: 1.0185x; 1.0185x over previous
//
#include <hip/hip_runtime.h>
#include <math.h>

#define MROWS 8192   // T*B flat rows
#define DM    512    // d_model
#define SEQL  2048   // attention sequence (rows per batch group)
#define HDIM  64

typedef __attribute__((ext_vector_type(4))) float floatx4;
typedef _Float16 half2v __attribute__((ext_vector_type(2)));
typedef _Float16 half4v __attribute__((ext_vector_type(4)));
typedef _Float16 half8v __attribute__((ext_vector_type(8)));

#define CEXP 0.18033688011f   // log2(e)/8 — folded into Wq/bq at prep time

// async global->LDS, 16B per lane; LDS dst must be uniform_base + lane*16
__device__ __forceinline__ void gll16(const void* g, void* l) {
    __builtin_amdgcn_global_load_lds(
        (const __attribute__((address_space(1))) unsigned int*)g,
        (__attribute__((address_space(3))) unsigned int*)l, 16, 0, 0);
}

__device__ __forceinline__ half4v pack4(float a, float b, float c, float d) {
    half2v lo = __builtin_bit_cast(half2v, __builtin_amdgcn_cvt_pkrtz(a, b));
    half2v hi = __builtin_bit_cast(half2v, __builtin_amdgcn_cvt_pkrtz(c, d));
    half4v r;
    r[0] = lo[0]; r[1] = lo[1]; r[2] = hi[0]; r[3] = hi[1];
    return r;
}

// ---------------------------------------------------------------------------
// transpose+cast 512x512 f32 weights -> f16 [N][K]; Wq (z==0) pre-scaled by CEXP
// ---------------------------------------------------------------------------
__global__ __launch_bounds__(256) void transw(const float* __restrict__ w0,
                                              const float* __restrict__ w1,
                                              const float* __restrict__ w2,
                                              const float* __restrict__ w3,
                                              _Float16* __restrict__ t0,
                                              _Float16* __restrict__ t1,
                                              _Float16* __restrict__ t2,
                                              _Float16* __restrict__ t3) {
    __shared__ float tile[32][33];
    const float* W = blockIdx.z == 0 ? w0 : (blockIdx.z == 1 ? w1 : (blockIdx.z == 2 ? w2 : w3));
    _Float16* T = blockIdx.z == 0 ? t0 : (blockIdx.z == 1 ? t1 : (blockIdx.z == 2 ? t2 : t3));
    const float sc = (blockIdx.z == 0) ? CEXP : 1.0f;
    const int tx = threadIdx.x & 31, ty = threadIdx.x >> 5;  // 32 x 8
    const int x = blockIdx.x * 32 + tx;
    const int y0 = blockIdx.y * 32;
#pragma unroll
    for (int i = 0; i < 4; ++i)
        tile[ty + i * 8][tx] = W[(size_t)(y0 + ty + i * 8) * DM + x];
    __syncthreads();
    const int xo = y0 + tx;
#pragma unroll
    for (int i = 0; i < 4; ++i)
        T[(size_t)(blockIdx.x * 32 + ty + i * 8) * DM + xo] = (_Float16)(tile[tx][ty + i * 8] * sc);
}

// ---------------------------------------------------------------------------
// Projection GEMM, 128x128 tile, BK=64 (r5 structure, unchanged).
// ---------------------------------------------------------------------------
__global__ __launch_bounds__(256, 3) void proj_gemm(
        const float* __restrict__ q32, const float* __restrict__ k32, const float* __restrict__ v32,
        const _Float16* __restrict__ Wq, const _Float16* __restrict__ Wk, const _Float16* __restrict__ Wv,
        const float* __restrict__ bq, const float* __restrict__ bk, const float* __restrict__ bv,
        _Float16* __restrict__ Qo, _Float16* __restrict__ Ko, _Float16* __restrict__ Vto) {
    __shared__ _Float16 As[128 * 64];   // 16 KB [m][k], xor-swizzled 16B groups
    __shared__ _Float16 Bs[128 * 64];   // 16 KB [n][k], xor-swizzled
    const int z = blockIdx.z;
    const float* A32    = z == 0 ? q32 : (z == 1 ? k32 : v32);
    const _Float16* Bt  = z == 0 ? Wq : (z == 1 ? Wk : Wv);
    const float* bias   = z == 0 ? bq : (z == 1 ? bk : bv);
    const float bscale  = z == 0 ? CEXP : 1.0f;

    const int tid = threadIdx.x;
    const int w = tid >> 6, wr = w >> 1, wc = w & 1;   // 2x2 wave grid
    const int l15 = tid & 15, quad = (tid & 63) >> 4;
    const int m0 = blockIdx.x * 128, n0 = blockIdx.y * 128;

    // A staging: 2 threads per row, 32 f32 each (8 float4 -> 4 swizzled 16B)
    const int arow = tid >> 1, ah = tid & 1;
    const float* Asrc = &A32[(size_t)(m0 + arow) * DM + ah * 32];
    _Float16* Adst = &As[arow * 64];
    const int asw = arow & 7;

    floatx4 acc[4][4];
#pragma unroll
    for (int i = 0; i < 4; ++i)
#pragma unroll
        for (int j = 0; j < 4; ++j) acc[i][j] = (floatx4){0.f, 0.f, 0.f, 0.f};

    for (int kt = 0; kt < DM / 64; ++kt) {   // 8 iters
        __syncthreads();
        // A reg-loads first (issued before gll16s: cast waits at vmcnt(4))
        floatx4 f[8];
        {
            const float* s = Asrc + (size_t)kt * 64;
#pragma unroll
            for (int q = 0; q < 8; ++q) f[q] = *(const floatx4*)&s[q * 4];
        }
        // B: 128 rows x 64 k = 1024 chunks of 16B -> 4 gll16/thread
#pragma unroll
        for (int i = 0; i < 4; ++i) {
            const int c = i * 256 + tid;
            const int row = c >> 3, g = c & 7;
            const int kg = g ^ (row & 7);
            gll16(&Bt[(size_t)(n0 + row) * DM + kt * 64 + kg * 8], &Bs[c * 8]);
        }
        // A cast + swizzled LDS writes
#pragma unroll
        for (int t = 0; t < 4; ++t) {
            half8v o;
            o[0] = (_Float16)f[2 * t][0]; o[1] = (_Float16)f[2 * t][1];
            o[2] = (_Float16)f[2 * t][2]; o[3] = (_Float16)f[2 * t][3];
            o[4] = (_Float16)f[2 * t + 1][0]; o[5] = (_Float16)f[2 * t + 1][1];
            o[6] = (_Float16)f[2 * t + 1][2]; o[7] = (_Float16)f[2 * t + 1][3];
            const int g = ah * 4 + t;
            *(half8v*)&Adst[(g ^ asw) * 8] = o;
        }
        __syncthreads();
#pragma unroll
        for (int ks = 0; ks < 2; ++ks) {
            half8v af[4], bf[4];
#pragma unroll
            for (int i = 0; i < 4; ++i) {
                const int row = wr * 64 + i * 16 + l15;
                af[i] = *(const half8v*)&As[row * 64 + (((ks * 4 + quad)) ^ (row & 7)) * 8];
            }
#pragma unroll
            for (int j = 0; j < 4; ++j) {
                const int row = wc * 64 + j * 16 + l15;
                bf[j] = *(const half8v*)&Bs[row * 64 + (((ks * 4 + quad)) ^ (row & 7)) * 8];
            }
#pragma unroll
            for (int i = 0; i < 4; ++i)
#pragma unroll
                for (int j = 0; j < 4; ++j)
                    acc[i][j] = __builtin_amdgcn_mfma_f32_16x16x32_f16(af[i], bf[j], acc[i][j], 0, 0, 0);
        }
    }
    // epilogue
#pragma unroll
    for (int j = 0; j < 4; ++j) {
        const int col = n0 + wc * 64 + j * 16 + l15;
        const float bv4 = bias[col] * bscale;
#pragma unroll
        for (int i = 0; i < 4; ++i) {
            const int rb = m0 + wr * 64 + i * 16 + quad * 4;
            if (z == 2) {   // Vt[g][col][seq]: 4 consecutive seq -> one 8B store
                const int g = rb >> 11, seq = rb & 2047;
                half4v pv;
#pragma unroll
                for (int r = 0; r < 4; ++r) pv[r] = (_Float16)(acc[i][j][r] + bv4);
                *(half4v*)&Vto[((size_t)g * DM + col) * SEQL + seq] = pv;
            } else {
                _Float16* oh = z == 0 ? Qo : Ko;
#pragma unroll
                for (int r = 0; r < 4; ++r)
                    oh[(size_t)(rb + r) * DM + col] = (_Float16)(acc[i][j][r] + bv4);
            }
        }
    }
}

// ---------------------------------------------------------------------------
// Output GEMM: out = O16 . Wo + bo.  A (normalized O, f16) staged via gll16
// directly.  block = 32 M x 256 N, BK=64, grid (2, 256).  (r8 version.)
// ---------------------------------------------------------------------------
__global__ __launch_bounds__(256, 4) void out_gemm(
        const _Float16* __restrict__ O16,
        const _Float16* __restrict__ Wo, const float* __restrict__ bo,
        float* __restrict__ out) {
    __shared__ _Float16 Bs[256 * 64];   // 32 KB
    __shared__ _Float16 As[32 * 64];    //  4 KB
    const int tid = threadIdx.x;
    const int w = tid >> 6;
    const int l15 = tid & 15, quad = (tid & 63) >> 4;
    const int n0 = blockIdx.x * 256, m0 = blockIdx.y * 32;

    // A gll16 geometry: 32 rows x 64 k = 256 chunks of 16B -> 1 per thread
    const int arow = tid >> 3, ag = tid & 7;
    const int akg = ag ^ (arow & 7);

    floatx4 acc[2][4];
#pragma unroll
    for (int i = 0; i < 2; ++i)
#pragma unroll
        for (int j = 0; j < 4; ++j) acc[i][j] = (floatx4){0.f, 0.f, 0.f, 0.f};

    for (int kt = 0; kt < DM / 64; ++kt) {   // 8 iters
        __syncthreads();
        // B: 256 rows x 64 k = 2048 chunks -> 8 gll16/thread
#pragma unroll
        for (int i = 0; i < 8; ++i) {
            const int c = i * 256 + tid;
            const int row = c >> 3, g = c & 7;
            const int kg = g ^ (row & 7);
            gll16(&Wo[(size_t)(n0 + row) * DM + kt * 64 + kg * 8], &Bs[c * 8]);
        }
        // A: 1 gll16/thread
        gll16(&O16[(size_t)(m0 + arow) * DM + kt * 64 + akg * 8], &As[tid * 8]);
        __syncthreads();
#pragma unroll
        for (int ks = 0; ks < 2; ++ks) {
            half8v af[2], bfr[4];
#pragma unroll
            for (int i = 0; i < 2; ++i) {
                const int row = i * 16 + l15;
                af[i] = *(const half8v*)&As[row * 64 + ((ks * 4 + quad) ^ (row & 7)) * 8];
            }
#pragma unroll
            for (int j = 0; j < 4; ++j) {
                const int row = w * 64 + j * 16 + l15;
                bfr[j] = *(const half8v*)&Bs[row * 64 + ((ks * 4 + quad) ^ (row & 7)) * 8];
            }
#pragma unroll
            for (int i = 0; i < 2; ++i)
#pragma unroll
                for (int j = 0; j < 4; ++j)
                    acc[i][j] = __builtin_amdgcn_mfma_f32_16x16x32_f16(af[i], bfr[j], acc[i][j], 0, 0, 0);
        }
    }
#pragma unroll
    for (int j = 0; j < 4; ++j) {
        const int col = n0 + w * 64 + j * 16 + l15;
        const float bv4 = bo[col];
#pragma unroll
        for (int i = 0; i < 2; ++i) {
            const int rb = m0 + i * 16 + quad * 4;
#pragma unroll
            for (int r = 0; r < 4; ++r)
                out[(size_t)(rb + r) * DM + col] = acc[i][j][r] + bv4;
        }
    }
}

// ---------------------------------------------------------------------------
// Flash attention, f16 MFMA, S^T orientation, fixed-scale softmax.
// r12: r10 structure (256 threads, 4 waves x 32 q-rows, q=128/block,
// 512 blocks, XCD swizzle, in-register normalization) with KVBLK=128:
// NIT 32->16 — halves the per-iteration fixed overhead (barrier convergence
// + waitcnt drain) that dominates (r10: ~4060 cy/iter vs ~1000 cy of work;
// occupancy/TLP/traffic levers all individually refuted r6/r9/r10/r11).
// Total staging, MFMA, and exp volume unchanged.  LDS 64 KB -> 2 blocks/CU
// (grid already caps residency at 2).
// grid (16 q-tiles, 32 (g,h) pairs); 256 threads.
// ---------------------------------------------------------------------------
__global__ __launch_bounds__(256, 2) void attn_mfma(const _Float16* __restrict__ Q16,
                                                    const _Float16* __restrict__ K16,
                                                    const _Float16* __restrict__ Vt,
                                                    _Float16* __restrict__ O16) {
    __shared__ _Float16 Ks[2][128 * 64];   // [key][d], xor-swizzled d-groups
    __shared__ _Float16 Vs[2][64 * 128];   // [d][key], xor-swizzled key-groups

    const int tid  = threadIdx.x;
    const int lane = tid & 63;
    const int l15  = lane & 15;
    const int quad = lane >> 4;

    // XCD swizzle: linear id -> chunked id so each XCD (id%8 under round-robin
    // dispatch) covers 64 consecutive logical blocks = 4 pairs x 16 q-tiles.
    const int idl  = blockIdx.y * 16 + blockIdx.x;     // 0..511
    const int swz  = (idl & 7) * 64 + (idl >> 3);      // bijective (512%8==0)
    const int pair = swz >> 4;
    const int grp  = pair >> 3;
    const int h    = pair & 7;
    const int q0   = (swz & 15) * 128;
    const int rQ   = grp * SEQL + q0 + (tid >> 6) * 32;
    const int cb   = h * HDIM;
    const int NIT  = SEQL / 128;   // 16

    const _Float16* Kbase = K16 + (size_t)grp * SEQL * DM + cb;
    const _Float16* Vbase = Vt + (size_t)grp * DM * SEQL + (size_t)cb * SEQL;

    // Q fragments (B-operand of S^T): B[n=qrow=l15][k=d=quad*8+j]
    half8v qf[2][2];
#pragma unroll
    for (int qt = 0; qt < 2; ++qt)
#pragma unroll
        for (int ks = 0; ks < 2; ++ks)
            qf[qt][ks] = *(const half8v*)&Q16[(size_t)(rQ + qt * 16 + l15) * DM + cb + ks * 32 + quad * 8];

    floatx4 oacc[2][4], lacc[2];
#pragma unroll
    for (int qt = 0; qt < 2; ++qt) {
        lacc[qt] = (floatx4){0.f, 0.f, 0.f, 0.f};
#pragma unroll
        for (int dt = 0; dt < 4; ++dt) oacc[qt][dt] = (floatx4){0.f, 0.f, 0.f, 0.f};
    }
    half4v ones;
    ones[0] = (_Float16)1.f; ones[1] = (_Float16)1.f; ones[2] = (_Float16)1.f; ones[3] = (_Float16)1.f;

    // staging for a 128-key tile: K 1024 chunks + V 1024 chunks -> 8/thread
#define STAGE(KT, B)                                                            \
    {                                                                           \
        _Float16* ksb = &Ks[B][0];                                              \
        _Float16* vsb = &Vs[B][0];                                              \
        _Pragma("unroll")                                                       \
        for (int i_ = 0; i_ < 8; ++i_) {                                        \
            const int c_ = i_ * 256 + tid;                                      \
            if (c_ < 1024) {                                                    \
                const int key_ = c_ >> 3, g_ = c_ & 7;                          \
                const int dg_ = g_ ^ (key_ & 7);                                \
                gll16(&Kbase[(size_t)((KT) * 128 + key_) * DM + dg_ * 8],       \
                      &ksb[c_ * 8]);                                            \
            } else {                                                            \
                const int cv_ = c_ - 1024;                                      \
                const int d_ = cv_ >> 4, g_ = cv_ & 15;                         \
                const int kg_ = g_ ^ (d_ & 7);                                  \
                gll16(&Vbase[(size_t)d_ * SEQL + (KT) * 128 + kg_ * 8],         \
                      &vsb[cv_ * 8]);                                           \
            }                                                                   \
        }                                                                       \
    }

    STAGE(0, 0)

    for (int it = 0; it < NIT; ++it) {
        const int cur = it & 1;
        __syncthreads();               // data for it ready; prev readers done
        if (it + 1 < NIT) STAGE(it + 1, cur ^ 1)

        const _Float16* ksb = &Ks[cur][0];
        const _Float16* vsb = &Vs[cur][0];

        // S^T = K . Q^T over 8 ktiles, processed in two halves of 4 to limit
        // live st registers; p = 2^s packed immediately per half.
        half4v pa[8][2];
#pragma unroll
        for (int half = 0; half < 2; ++half) {
            floatx4 st[4][2];
#pragma unroll
            for (int k4 = 0; k4 < 4; ++k4) {
                const int ktile = half * 4 + k4;
                const int key = ktile * 16 + l15;
                const half8v kf0 = *(const half8v*)&ksb[key * 64 + ((0 + quad) ^ (key & 7)) * 8];
                const half8v kf1 = *(const half8v*)&ksb[key * 64 + ((4 + quad) ^ (key & 7)) * 8];
#pragma unroll
                for (int qt = 0; qt < 2; ++qt) {
                    floatx4 z = {0.f, 0.f, 0.f, 0.f};
                    z = __builtin_amdgcn_mfma_f32_16x16x32_f16(kf0, qf[qt][0], z, 0, 0, 0);
                    st[k4][qt] = __builtin_amdgcn_mfma_f32_16x16x32_f16(kf1, qf[qt][1], z, 0, 0, 0);
                }
            }
#pragma unroll
            for (int k4 = 0; k4 < 4; ++k4)
#pragma unroll
                for (int qt = 0; qt < 2; ++qt)
                    pa[half * 4 + k4][qt] = pack4(__builtin_amdgcn_exp2f(st[k4][qt][0]),
                                                  __builtin_amdgcn_exp2f(st[k4][qt][1]),
                                                  __builtin_amdgcn_exp2f(st[k4][qt][2]),
                                                  __builtin_amdgcn_exp2f(st[k4][qt][3]));
        }

        // l += P . ones  (same C-layout rows as O)
#pragma unroll
        for (int qt = 0; qt < 2; ++qt)
#pragma unroll
            for (int ktile = 0; ktile < 8; ++ktile)
                lacc[qt] = __builtin_amdgcn_mfma_f32_16x16x16f16(pa[ktile][qt], ones, lacc[qt], 0, 0, 0);

        // O += P . V : B[k=key=quad*4+j][n=d=l15] from Vs[d][128 keys]
#pragma unroll
        for (int dt = 0; dt < 4; ++dt) {
            const int d = dt * 16 + l15;
#pragma unroll
            for (int ktile = 0; ktile < 8; ++ktile) {
                const int G = ktile * 2 + (quad >> 1);            // 16B group 0..15
                const int slot = G ^ (d & 7);
                const half4v vf = *(const half4v*)&vsb[d * 128 + slot * 8 + (quad & 1) * 4];
#pragma unroll
                for (int qt = 0; qt < 2; ++qt)
                    oacc[qt][dt] = __builtin_amdgcn_mfma_f32_16x16x16f16(pa[ktile][qt], vf, oacc[qt][dt], 0, 0, 0);
            }
        }
    }

    // epilogue: normalize in-register (lacc rows == oacc rows) + f16 store
#pragma unroll
    for (int qt = 0; qt < 2; ++qt)
#pragma unroll
        for (int r = 0; r < 4; ++r) {
            const int qrow = rQ + qt * 16 + quad * 4 + r;
            const size_t rowoff = (size_t)qrow * DM + cb;
            const float inv = 1.0f / lacc[qt][r];
#pragma unroll
            for (int dt = 0; dt < 4; ++dt)
                O16[rowoff + dt * 16 + l15] = (_Float16)(oacc[qt][dt][r] * inv);
        }
}

// ---------------------------------------------------------------------------
extern "C" void kernel_launch(void* const* d_in, const int* in_sizes, int n_in,
                              void* d_out, int out_size, void* d_ws, size_t ws_size,
                              hipStream_t stream) {
    const float* key_in   = (const float*)d_in[0];
    const float* value_in = (const float*)d_in[1];
    const float* query_in = (const float*)d_in[2];
    const float* Wk = (const float*)d_in[3];
    const float* bk = (const float*)d_in[4];
    const float* Wv = (const float*)d_in[5];
    const float* bv = (const float*)d_in[6];
    const float* Wq = (const float*)d_in[7];
    const float* bq = (const float*)d_in[8];
    const float* Wo = (const float*)d_in[9];
    const float* bo = (const float*)d_in[10];
    float* out = (float*)d_out;

    const size_t MAT = (size_t)MROWS * DM;   // 4M elems
    _Float16* Q16  = (_Float16*)d_ws;        // 8 MB
    _Float16* K16  = Q16 + MAT;              // 8 MB
    _Float16* Vtb  = K16 + MAT;              // 8 MB (transposed V, written by proj z=2)
    _Float16* Wqt  = Vtb + MAT;              // 0.5 MB each
    _Float16* Wkt  = Wqt + DM * DM;
    _Float16* Wvt  = Wkt + DM * DM;
    _Float16* Wot  = Wvt + DM * DM;
    _Float16* O16  = Wot + DM * DM;          // 8 MB (normalized attn output)

    const dim3 blk(256);

    transw<<<dim3(16, 16, 4), blk, 0, stream>>>(Wq, Wk, Wv, Wo, Wqt, Wkt, Wvt, Wot);

    // fused cast + Q/K/V projections; V writes Vt layout directly
    proj_gemm<<<dim3(MROWS / 128, DM / 128, 3), blk, 0, stream>>>(
        query_in, key_in, value_in, Wqt, Wkt, Wvt, bq, bk, bv, Q16, K16, Vtb);

    // full-key attention, XCD-swizzled, KVBLK=128, in-register normalization
    attn_mfma<<<dim3(SEQL / 128, 32), blk, 0, stream>>>(Q16, K16, Vtb, O16);

    // output GEMM (plain m97 structure, both operands via gll16)
    out_gemm<<<dim3(2, MROWS / 32), blk, 0, stream>>>(O16, Wot, bo, out);
}